// Round 1
// baseline (146.994 us; speedup 1.0000x reference)
//
#include <hip/hip_runtime.h>

// VectorQuantizer: z[32,32,64,64] f32 (BCHW), emb[1024,32] f32.
// out = concat( z_q[32,32,64,64] f32 , idx[131072] stored as f32 values ).
//
// R17: f16 single-MFMA scan. The bf16 hi/lo 3-MFMA split (R13..R16) is
// replaced by ONE f16 16x16x32 MFMA: f16's 11-bit significand bounds the
// scan error at 2eps <= 2*2*2^-12*max|2e|*sum|z| ~= 9.2e-5 < MARGIN=1e-4
// even fully adversarially aligned (sum|z_k| <= 48 at 6.6 sigma), so the
// candidate set provably still contains the true argmin. Everything that
// decides the final idx (ballot classification, numpy-bit-exact fp32
// rescore, listB fixup) is unchanged from the validated R16 kernel.
// Cascade: el/sel/azl deleted, LDS 38.4K -> 19.97K (8 blocks/CU,
// __launch_bounds__(256,8)), fragment read is one aligned ds_read_b128
// on unpadded 64B rows (uniform 8 dwords/bank).
// 3 kernels total (prep_e is 4 blocks).

#define NUM_EMB 1024
#define EMB_DIM 32
#define HW      4096
#define BATCH   32
#define N_TOT   (BATCH * HW)  // 131072
#define NSPLIT  4
#define CODES_PER (NUM_EMB / NSPLIT)
#define MARGIN  1.0e-4f
#define CHUNK   256

// ws layout (unchanged vs R16; old el region now unused)
#define OFF_BQ    0u
#define OFF_EH    4096u
#define OFF_CTRS  135168u     // [1]=listB count ([0] unused)
#define OFF_LISTB 135184u
#define WS_NEED   659472u
#define WS_NEED_R7 (4096u + 4u * 131072u * 8u)

using f16x8 = __attribute__((ext_vector_type(8))) _Float16;
using f32x4 = __attribute__((ext_vector_type(4))) float;

#define REPEAT32(M) \
    M(0)  M(1)  M(2)  M(3)  M(4)  M(5)  M(6)  M(7)  \
    M(8)  M(9)  M(10) M(11) M(12) M(13) M(14) M(15) \
    M(16) M(17) M(18) M(19) M(20) M(21) M(22) M(23) \
    M(24) M(25) M(26) M(27) M(28) M(29) M(30) M(31)

__device__ __forceinline__ float pairwise_sq32(const float* __restrict__ e) {
    float r0 = __fmul_rn(e[0], e[0]), r1 = __fmul_rn(e[1], e[1]);
    float r2 = __fmul_rn(e[2], e[2]), r3 = __fmul_rn(e[3], e[3]);
    float r4 = __fmul_rn(e[4], e[4]), r5 = __fmul_rn(e[5], e[5]);
    float r6 = __fmul_rn(e[6], e[6]), r7 = __fmul_rn(e[7], e[7]);
#pragma unroll
    for (int i = 8; i < 32; i += 8) {
        r0 = __fadd_rn(r0, __fmul_rn(e[i + 0], e[i + 0]));
        r1 = __fadd_rn(r1, __fmul_rn(e[i + 1], e[i + 1]));
        r2 = __fadd_rn(r2, __fmul_rn(e[i + 2], e[i + 2]));
        r3 = __fadd_rn(r3, __fmul_rn(e[i + 3], e[i + 3]));
        r4 = __fadd_rn(r4, __fmul_rn(e[i + 4], e[i + 4]));
        r5 = __fadd_rn(r5, __fmul_rn(e[i + 5], e[i + 5]));
        r6 = __fadd_rn(r6, __fmul_rn(e[i + 6], e[i + 6]));
        r7 = __fadd_rn(r7, __fmul_rn(e[i + 7], e[i + 7]));
    }
    return __fadd_rn(__fadd_rn(__fadd_rn(r0, r1), __fadd_rn(r2, r3)),
                     __fadd_rn(__fadd_rn(r4, r5), __fadd_rn(r6, r7)));
}

__device__ __forceinline__ void store_row16(unsigned short* dst,
                                            const unsigned short* v) {
    unsigned w[16];
#pragma unroll
    for (int i = 0; i < 16; ++i)
        w[i] = (unsigned)v[2 * i] | ((unsigned)v[2 * i + 1] << 16);
    uint4* d4 = (uint4*)dst;
    d4[0] = make_uint4(w[0], w[1], w[2], w[3]);
    d4[1] = make_uint4(w[4], w[5], w[6], w[7]);
    d4[2] = make_uint4(w[8], w[9], w[10], w[11]);
    d4[3] = make_uint4(w[12], w[13], w[14], w[15]);
}

// ---- prep_e: bq exact + (-2e) f16 + zero ctrs -----------------------------
__global__ __launch_bounds__(256) void vq_prep_e(
        const float* __restrict__ emb, float* __restrict__ bq,
        unsigned short* __restrict__ eh, int* __restrict__ ctrs) {
    const int g = blockIdx.x * 256 + threadIdx.x;
    if (g < 2) ctrs[g] = 0;
    if (g >= NUM_EMB) return;
    const float* e = emb + g * EMB_DIM;
    bq[g] = pairwise_sq32(e);
    unsigned short h[32];
#pragma unroll
    for (int c = 0; c < 32; ++c) {
        _Float16 hv = (_Float16)(-2.0f * e[c]);   // *2 exact, single RNE round
        h[c] = __builtin_bit_cast(unsigned short, hv);
    }
    store_row16(eh + (size_t)g * 32, h);
}

// ---- exact-rescore building blocks (verified numpy-fp32 chain) ------------
#define LOADZ(c) float z##c = zp[(size_t)(c) * HW];
#define Z_SQ_A()                                                              \
    float r0 = __fmul_rn(z0, z0), r1 = __fmul_rn(z1, z1);                     \
    float r2 = __fmul_rn(z2, z2), r3 = __fmul_rn(z3, z3);                     \
    float r4 = __fmul_rn(z4, z4), r5 = __fmul_rn(z5, z5);                     \
    float r6 = __fmul_rn(z6, z6), r7 = __fmul_rn(z7, z7);                     \
    r0 = __fadd_rn(r0, __fmul_rn(z8,  z8));  r0 = __fadd_rn(r0, __fmul_rn(z16, z16)); \
    r0 = __fadd_rn(r0, __fmul_rn(z24, z24));                                  \
    r1 = __fadd_rn(r1, __fmul_rn(z9,  z9));  r1 = __fadd_rn(r1, __fmul_rn(z17, z17)); \
    r1 = __fadd_rn(r1, __fmul_rn(z25, z25));                                  \
    r2 = __fadd_rn(r2, __fmul_rn(z10, z10)); r2 = __fadd_rn(r2, __fmul_rn(z18, z18)); \
    r2 = __fadd_rn(r2, __fmul_rn(z26, z26));                                  \
    r3 = __fadd_rn(r3, __fmul_rn(z11, z11)); r3 = __fadd_rn(r3, __fmul_rn(z19, z19)); \
    r3 = __fadd_rn(r3, __fmul_rn(z27, z27));                                  \
    r4 = __fadd_rn(r4, __fmul_rn(z12, z12)); r4 = __fadd_rn(r4, __fmul_rn(z20, z20)); \
    r4 = __fadd_rn(r4, __fmul_rn(z28, z28));                                  \
    r5 = __fadd_rn(r5, __fmul_rn(z13, z13)); r5 = __fadd_rn(r5, __fmul_rn(z21, z21)); \
    r5 = __fadd_rn(r5, __fmul_rn(z29, z29));                                  \
    r6 = __fadd_rn(r6, __fmul_rn(z14, z14)); r6 = __fadd_rn(r6, __fmul_rn(z22, z22)); \
    r6 = __fadd_rn(r6, __fmul_rn(z30, z30));                                  \
    r7 = __fadd_rn(r7, __fmul_rn(z15, z15)); r7 = __fadd_rn(r7, __fmul_rn(z23, z23)); \
    r7 = __fadd_rn(r7, __fmul_rn(z31, z31));                                  \
    const float a = __fadd_rn(                                                \
        __fadd_rn(__fadd_rn(r0, r1), __fadd_rn(r2, r3)),                      \
        __fadd_rn(__fadd_rn(r4, r5), __fadd_rn(r6, r7)));

#define FMA1(k) m = __fmaf_rn(z##k, e[(k)], m);
#define EXACT_KEY(jv)                                                         \
    {                                                                         \
        const float* e = emb + (size_t)(jv) * EMB_DIM;                        \
        float m = 0.0f;                                                       \
        REPEAT32(FMA1)                                                        \
        float d = __fsub_rn(__fadd_rn(a, bq[(jv)]), __fmul_rn(2.0f, m));      \
        unsigned u = __float_as_uint(d);                                      \
        u = (u & 0x80000000u) ? ~u : (u | 0x80000000u);                       \
        unsigned long long kk =                                               \
            ((unsigned long long)u << 32) | (unsigned)(jv);                   \
        if (kk < bestk) bestk = kk;                                           \
    }

// ---- mega filter: scan + classify + rescore + writeback -------------------
// Block = 256 thr = 4 waves; wave: 32 queries (2 tiles); block: 128 queries.
// LDS phase 1: seh/sbq staging (17408 B). Phase 2 (aliased):
// sz/scand/sdest/sidx (19968 B). 8 blocks/CU.
__global__ __launch_bounds__(256, 8) void vq_filter(
        const float* __restrict__ z, const float* __restrict__ emb,
        const unsigned short* __restrict__ eh,
        const float* __restrict__ bq, int* __restrict__ ctrs,
        int* __restrict__ listB, float* __restrict__ out_zq,
        float* __restrict__ out_idx) {
    __shared__ __align__(16) char smem[19968];
    _Float16* seh = (_Float16*)smem;           // [0, 16384)  256 rows x 64 B
    float*    sbq = (float*)(smem + 16384);    // [16384, 17408)
    // phase-2 aliases (scan complete, barrier-separated):
    float* sz    = (float*)smem;               // 128*33*4 = 16896
    int*   scand = (int*)(smem + 16896);       // 128*4*4  = 2048
    int*   sdest = (int*)(smem + 18944);       // 512
    int*   sidx  = (int*)(smem + 19456);       // 512
    __shared__ int swt[2];
    __shared__ int sbase1;

    const int tid  = threadIdx.x;
    const int lane = tid & 63;
    const int wv   = tid >> 6;
    const int cloc = lane & 15, quad = lane >> 4;
    const int qbase = blockIdx.x * 128 + wv * 32;

    // A-fragments from z (f16 RNE); keep the raw floats for the exact phase
    float zf[2][8];
    f16x8 az[2];
#pragma unroll
    for (int t = 0; t < 2; ++t) {
        const int q  = qbase + t * 16 + cloc;
        const int b  = q >> 12;
        const int hw = q & 4095;
        const float* zb = z + ((size_t)b * EMB_DIM + quad * 8) * HW + hw;
#pragma unroll
        for (int k = 0; k < 8; ++k) {
            float v = zb[(size_t)k * HW];
            zf[t][k] = v;
            az[t][k] = (_Float16)v;            // v_cvt_f16_f32, RNE
        }
    }

    float m1[2][4], m2[2][4];
    int   i1[2][4];
#pragma unroll
    for (int t = 0; t < 2; ++t)
#pragma unroll
        for (int r = 0; r < 4; ++r) {
            m1[t][r] = 3.4e38f; m2[t][r] = 3.4e38f; i1[t][r] = 0;
        }

    for (int ch = 0; ch < 4; ++ch) {
        if (ch) __syncthreads();
        {   // stage 256 codes x 32 f16 = 16 KB + bq chunk
            const uint4* src = (const uint4*)(eh + (size_t)ch * CHUNK * 32);
            uint4* dst = (uint4*)seh;
#pragma unroll
            for (int i = 0; i < 4; ++i) dst[i * 256 + tid] = src[i * 256 + tid];
            sbq[tid] = bq[ch * CHUNK + tid];
        }
        __syncthreads();

        for (int jt = 0; jt < 16; ++jt) {
            const int row = jt * 16 + cloc;
            f16x8 ef = *(const f16x8*)(seh + row * 32 + quad * 8); // b128
            const float bqv = sbq[row];
            const int jts = ch * 16 + jt;
#pragma unroll
            for (int t = 0; t < 2; ++t) {
                f32x4 acc = {bqv, bqv, bqv, bqv};
                acc = __builtin_amdgcn_mfma_f32_16x16x32_f16(az[t], ef, acc, 0, 0, 0);
#pragma unroll
                for (int r = 0; r < 4; ++r) {
                    const float tt = acc[r];
                    const bool l1 = tt < m1[t][r];
                    m2[t][r] = __builtin_amdgcn_fmed3f(tt, m1[t][r], m2[t][r]);
                    m1[t][r] = fminf(m1[t][r], tt);
                    i1[t][r] = l1 ? jts : i1[t][r];
                }
            }
        }
    }
    __syncthreads();   // scan done everywhere; staging LDS may be reused

    // park z floats: sz[ql*33 + quad*8 + k]
#pragma unroll
    for (int t = 0; t < 2; ++t) {
        const int ql = wv * 32 + t * 16 + cloc;
#pragma unroll
        for (int k = 0; k < 8; ++k) sz[ql * 33 + quad * 8 + k] = zf[t][k];
    }

    // per-query global min across the 16 cloc lanes
    float g[2][4];
#pragma unroll
    for (int t = 0; t < 2; ++t)
#pragma unroll
        for (int r = 0; r < 4; ++r) g[t][r] = m1[t][r];
#pragma unroll
    for (int off = 1; off < 16; off <<= 1)
#pragma unroll
        for (int t = 0; t < 2; ++t)
#pragma unroll
            for (int r = 0; r < 4; ++r)
                g[t][r] = fminf(g[t][r], __shfl_xor(g[t][r], off, 64));

    // classification -> LDS, no atomics (ballot-prefix candidate slots)
#pragma unroll
    for (int t = 0; t < 2; ++t)
#pragma unroll
        for (int r = 0; r < 4; ++r) {
            const float thr = g[t][r] + MARGIN;
            const int   ql  = wv * 32 + t * 16 + quad * 4 + r;
            const bool  f1  = m1[t][r] <= thr;
            const bool  f2  = m2[t][r] <= thr;
            const unsigned long long b1 = __ballot(f1);
            const unsigned long long b2 = __ballot(f2);
            const unsigned mk1 = (unsigned)(b1 >> (quad * 16)) & 0xFFFFu;
            const unsigned mk2 = (unsigned)(b2 >> (quad * 16)) & 0xFFFFu;
            const int pc  = __popc(mk1);
            const int ldr = __ffs(mk1) - 1;   // mk1 != 0 (global-min lane)
            if (mk2 | (unsigned)(pc > 4)) {
                if (cloc == ldr) sdest[ql] = 5;
            } else {
                if (f1)
                    scand[(ql << 2) + __popc(mk1 & ((1u << cloc) - 1u))] =
                        i1[t][r] * 16 + cloc;
                if (cloc == ldr) sdest[ql] = pc;
            }
        }
    __syncthreads();

    // listB compaction (1 atomic/block) + exact rescore for pc 2..4
    int d = 0, pre = 0;
    if (tid < 128) {
        d = sdest[tid];
        const unsigned long long mB = __ballot(d == 5);
        pre = (int)__popcll(mB & ((1ull << lane) - 1ull));
        if (lane == 0) swt[tid >> 6] = (int)__popcll(mB);
    }
    __syncthreads();
    if (tid == 0) {
        const int tB = swt[0] + swt[1];
        sbase1 = tB ? atomicAdd(&ctrs[1], tB) : 0;
    }
    __syncthreads();
    if (tid < 128) {
        if (d == 5) {
            listB[sbase1 + ((tid >> 6) ? swt[0] : 0) + pre] =
                blockIdx.x * 128 + tid;
        } else if (d == 1) {
            sidx[tid] = scand[tid << 2];
        } else {
            const float* szp = &sz[tid * 33];
#define LOADZ2(c) const float z##c = szp[(c)];
            REPEAT32(LOADZ2)
#undef LOADZ2
            Z_SQ_A()
            unsigned long long bestk = ~0ull;
            for (int k = 0; k < d; ++k) {
                const int jv = scand[(tid << 2) + k];
                EXACT_KEY(jv)
            }
            sidx[tid] = (int)(unsigned)(bestk & 0xffffffffu);
        }
    }
    __syncthreads();

    // writeback: idx + z_q for all non-B queries (coalesced across tid)
    if (tid < 128 && d != 5) {
        const int n    = blockIdx.x * 128 + tid;
        const int bidx = sidx[tid];
        out_idx[n] = (float)bidx;
        const int b  = n >> 12;
        const int hw = n & 4095;
        const float4* er = (const float4*)(emb + (size_t)bidx * EMB_DIM);
        float* op = out_zq + (size_t)b * EMB_DIM * HW + hw;
#pragma unroll
        for (int c4 = 0; c4 < 8; ++c4) {
            float4 v = er[c4];
            op[(size_t)(c4 * 4 + 0) * HW] = v.x;
            op[(size_t)(c4 * 4 + 1) * HW] = v.y;
            op[(size_t)(c4 * 4 + 2) * HW] = v.z;
            op[(size_t)(c4 * 4 + 3) * HW] = v.w;
        }
    }
}

// ---- fixup: list B, block-per-query exact full scan + idx + z_q -----------
__global__ __launch_bounds__(256) void vq_fixup(
        const float* __restrict__ z, const float* __restrict__ emb,
        const float* __restrict__ bq, const int* __restrict__ ctrs,
        const int* __restrict__ listB, float* __restrict__ out_zq,
        float* __restrict__ out_idx) {
    __shared__ unsigned long long bs[256];
    const int tid = threadIdx.x;
    const int total = ctrs[1];

    for (int it = blockIdx.x; it < total; it += gridDim.x) {
        const int n  = listB[it];
        const int b  = n >> 12;
        const int hw = n & 4095;
        const float* zp = z + (size_t)b * EMB_DIM * HW + hw;  // broadcast
        REPEAT32(LOADZ)
        Z_SQ_A()
        unsigned long long bestk = ~0ull;
#pragma unroll
        for (int k = 0; k < 4; ++k) { const int jv = tid * 4 + k; EXACT_KEY(jv) }
        bs[tid] = bestk;
        __syncthreads();
        for (int off = 128; off > 0; off >>= 1) {
            if (tid < off && bs[tid + off] < bs[tid]) bs[tid] = bs[tid + off];
            __syncthreads();
        }
        const int bidx = (int)(unsigned)(bs[0] & 0xffffffffu);
        if (tid == 0) out_idx[n] = (float)bidx;
        if (tid < EMB_DIM)
            out_zq[(size_t)b * EMB_DIM * HW + (size_t)tid * HW + hw] =
                emb[(size_t)bidx * EMB_DIM + tid];
        __syncthreads();
    }
}

// ================== proven R7/R5 exhaustive fallback =======================
#define SCAN_GROUP4(j)                                                        \
    {                                                                         \
        const float* e = emb + (size_t)(j) * EMB_DIM;                         \
        const float bq0 = bq[(j) + 0], bq1 = bq[(j) + 1];                     \
        const float bq2 = bq[(j) + 2], bq3 = bq[(j) + 3];                     \
        float m0 = 0.0f, m1 = 0.0f, m2 = 0.0f, m3 = 0.0f;                     \
        REPEAT32(FMA_K)                                                       \
        float d0 = __fsub_rn(__fadd_rn(a, bq0), __fmul_rn(2.0f, m0));         \
        float d1 = __fsub_rn(__fadd_rn(a, bq1), __fmul_rn(2.0f, m1));         \
        float d2 = __fsub_rn(__fadd_rn(a, bq2), __fmul_rn(2.0f, m2));         \
        float d3 = __fsub_rn(__fadd_rn(a, bq3), __fmul_rn(2.0f, m3));         \
        if (d0 < best) { best = d0; bidx = (j) + 0; }                         \
        if (d1 < best) { best = d1; bidx = (j) + 1; }                         \
        if (d2 < best) { best = d2; bidx = (j) + 2; }                         \
        if (d3 < best) { best = d3; bidx = (j) + 3; }                         \
    }
#define FMA_K(k) \
        m0 = __fmaf_rn(z##k, e[0 * EMB_DIM + (k)], m0); \
        m1 = __fmaf_rn(z##k, e[1 * EMB_DIM + (k)], m1); \
        m2 = __fmaf_rn(z##k, e[2 * EMB_DIM + (k)], m2); \
        m3 = __fmaf_rn(z##k, e[3 * EMB_DIM + (k)], m3);

__global__ __launch_bounds__(256) void vq_sqnorm_kernel(
        const float* __restrict__ emb, float* __restrict__ bq) {
    int j = blockIdx.x * 256 + threadIdx.x;
    if (j < NUM_EMB) bq[j] = pairwise_sq32(emb + j * EMB_DIM);
}

__global__ __launch_bounds__(128, 4) void vq_partial_kernel(
        const float* __restrict__ z, const float* __restrict__ emb,
        const float* __restrict__ bq, unsigned long long* __restrict__ pk) {
    const int n  = blockIdx.x * 128 + threadIdx.x;
    const int b  = n >> 12;
    const int hw = n & 4095;
    const float* zp = z + (size_t)b * EMB_DIM * HW + hw;
    REPEAT32(LOADZ)
    Z_SQ_A()
    const int j0 = blockIdx.y * CODES_PER;
    float best = 3.4e38f;
    int   bidx = j0;
    for (int j = j0; j < j0 + CODES_PER; j += 4) SCAN_GROUP4(j)
    pk[(size_t)blockIdx.y * N_TOT + n] =
        ((unsigned long long)__float_as_uint(best) << 32) | (unsigned)bidx;
}

__global__ __launch_bounds__(256, 2) void vq_main_kernel(
        const float* __restrict__ z, const float* __restrict__ emb,
        const float* __restrict__ bq, float* __restrict__ out_zq,
        float* __restrict__ out_idx) {
    const int n  = blockIdx.x * 256 + threadIdx.x;
    const int b  = n >> 12;
    const int hw = n & 4095;
    const float* zp = z + (size_t)b * EMB_DIM * HW + hw;
    REPEAT32(LOADZ)
    Z_SQ_A()
    float best = 3.4e38f;
    int   bidx = 0;
    for (int j = 0; j < NUM_EMB; j += 4) SCAN_GROUP4(j)
    out_idx[n] = (float)bidx;
    const float* eb = emb + (size_t)bidx * EMB_DIM;
    float* op = out_zq + (size_t)b * EMB_DIM * HW + hw;
#pragma unroll
    for (int cc = 0; cc < EMB_DIM; ++cc) op[(size_t)cc * HW] = eb[cc];
}

__global__ __launch_bounds__(256) void vq_combine_kernel(
        const float* __restrict__ emb,
        const unsigned long long* __restrict__ pk,
        float* __restrict__ out_zq, float* __restrict__ out_idx) {
    const int n = blockIdx.x * 256 + threadIdx.x;
    unsigned long long m = pk[n];
#pragma unroll
    for (int y = 1; y < NSPLIT; ++y) {
        unsigned long long v = pk[(size_t)y * N_TOT + n];
        if (v < m) m = v;
    }
    const int bidx = (int)(unsigned)(m & 0xffffffffu);
    out_idx[n] = (float)bidx;
    const int b  = n >> 12;
    const int hw = n & 4095;
    const float* eb = emb + (size_t)bidx * EMB_DIM;
    float* op = out_zq + (size_t)b * EMB_DIM * HW + hw;
#pragma unroll
    for (int cc = 0; cc < EMB_DIM; ++cc) op[(size_t)cc * HW] = eb[cc];
}

extern "C" void kernel_launch(void* const* d_in, const int* in_sizes, int n_in,
                              void* d_out, int out_size, void* d_ws,
                              size_t ws_size, hipStream_t stream) {
    const float* z   = (const float*)d_in[0];
    const float* emb = (const float*)d_in[1];
    char* ws = (char*)d_ws;
    float* out0 = (float*)d_out;
    float* out1 = out0 + (size_t)BATCH * EMB_DIM * HW;

    if (ws_size >= WS_NEED) {
        float*          bq    = (float*)(ws + OFF_BQ);
        unsigned short* eh    = (unsigned short*)(ws + OFF_EH);
        int*            ctrs  = (int*)(ws + OFF_CTRS);
        int*            listB = (int*)(ws + OFF_LISTB);

        vq_prep_e<<<4, 256, 0, stream>>>(emb, bq, eh, ctrs);
        vq_filter<<<N_TOT / 128, 256, 0, stream>>>(z, emb, eh, bq, ctrs,
                                                   listB, out0, out1);
        vq_fixup<<<1024, 256, 0, stream>>>(z, emb, bq, ctrs, listB,
                                           out0, out1);
    } else if (ws_size >= WS_NEED_R7) {
        float* bq = (float*)ws;
        unsigned long long* pk = (unsigned long long*)(ws + 4096);
        vq_sqnorm_kernel<<<NUM_EMB / 256, 256, 0, stream>>>(emb, bq);
        vq_partial_kernel<<<dim3(N_TOT / 128, NSPLIT), 128, 0, stream>>>(
            z, emb, bq, pk);
        vq_combine_kernel<<<N_TOT / 256, 256, 0, stream>>>(emb, pk, out0, out1);
    } else {
        float* bq = (float*)ws;
        vq_sqnorm_kernel<<<NUM_EMB / 256, 256, 0, stream>>>(emb, bq);
        vq_main_kernel<<<N_TOT / 256, 256, 0, stream>>>(z, emb, bq, out0, out1);
    }
}

// Round 2
// 131.722 us; speedup vs baseline: 1.1159x; 1.1159x over previous
//
#include <hip/hip_runtime.h>

// VectorQuantizer: z[32,32,64,64] f32 (BCHW), emb[1024,32] f32.
// out = concat( z_q[32,32,64,64] f32 , idx[131072] stored as f32 values ).
//
// R18: two kernels (prep_e + mega filter), spill-free.
//  - f16 single-MFMA scan (validated R17: absmax unchanged; error bound
//    2*2^-12*max|2e|*sum|z| ~= 9.2e-5 < MARGIN=1e-4).
//  - Packed-key min tracking: scan values d' = bq_j - 2<z,e_j> have
//    |d'| <~ 0.1 so clearing low-6 mantissa bits and packing the code
//    sub-index (jt in-loop, ch merged per chunk) perturbs comparisons by
//    < 5e-7 << MARGIN. Per-distance update = and_or + min + med3 (3 VALU,
//    was 4), and i1[2][4] registers are deleted.
//  - No zf registers / LDS z-parking: phase-2 exact rescore reloads z from
//    global (L2-hot, coalesced). Scan live state ~55 VGPR; launch_bounds
//    (256,4) => no spill (R17 post-mortem: (256,8) forced 32-VGPR spill,
//    hbm_bytes 59->130 MB).
//  - vq_fixup folded into the filter block: per-block local listB (no
//    atomics, no global listB), exact 1024-code in-block scan per entry.
// Classification/margin/exact-rescore logic identical to validated R16.

#define NUM_EMB 1024
#define EMB_DIM 32
#define HW      4096
#define BATCH   32
#define N_TOT   (BATCH * HW)  // 131072
#define NSPLIT  4
#define CODES_PER (NUM_EMB / NSPLIT)
#define MARGIN  1.0e-4f
#define CHUNK   256

// ws layout
#define OFF_BQ    0u
#define OFF_EH    4096u
#define WS_NEED   69632u
#define WS_NEED_R7 (4096u + 4u * 131072u * 8u)

using f16x8 = __attribute__((ext_vector_type(8))) _Float16;
using f32x4 = __attribute__((ext_vector_type(4))) float;

#define REPEAT32(M) \
    M(0)  M(1)  M(2)  M(3)  M(4)  M(5)  M(6)  M(7)  \
    M(8)  M(9)  M(10) M(11) M(12) M(13) M(14) M(15) \
    M(16) M(17) M(18) M(19) M(20) M(21) M(22) M(23) \
    M(24) M(25) M(26) M(27) M(28) M(29) M(30) M(31)

__device__ __forceinline__ float pairwise_sq32(const float* __restrict__ e) {
    float r0 = __fmul_rn(e[0], e[0]), r1 = __fmul_rn(e[1], e[1]);
    float r2 = __fmul_rn(e[2], e[2]), r3 = __fmul_rn(e[3], e[3]);
    float r4 = __fmul_rn(e[4], e[4]), r5 = __fmul_rn(e[5], e[5]);
    float r6 = __fmul_rn(e[6], e[6]), r7 = __fmul_rn(e[7], e[7]);
#pragma unroll
    for (int i = 8; i < 32; i += 8) {
        r0 = __fadd_rn(r0, __fmul_rn(e[i + 0], e[i + 0]));
        r1 = __fadd_rn(r1, __fmul_rn(e[i + 1], e[i + 1]));
        r2 = __fadd_rn(r2, __fmul_rn(e[i + 2], e[i + 2]));
        r3 = __fadd_rn(r3, __fmul_rn(e[i + 3], e[i + 3]));
        r4 = __fadd_rn(r4, __fmul_rn(e[i + 4], e[i + 4]));
        r5 = __fadd_rn(r5, __fmul_rn(e[i + 5], e[i + 5]));
        r6 = __fadd_rn(r6, __fmul_rn(e[i + 6], e[i + 6]));
        r7 = __fadd_rn(r7, __fmul_rn(e[i + 7], e[i + 7]));
    }
    return __fadd_rn(__fadd_rn(__fadd_rn(r0, r1), __fadd_rn(r2, r3)),
                     __fadd_rn(__fadd_rn(r4, r5), __fadd_rn(r6, r7)));
}

__device__ __forceinline__ void store_row16(unsigned short* dst,
                                            const unsigned short* v) {
    unsigned w[16];
#pragma unroll
    for (int i = 0; i < 16; ++i)
        w[i] = (unsigned)v[2 * i] | ((unsigned)v[2 * i + 1] << 16);
    uint4* d4 = (uint4*)dst;
    d4[0] = make_uint4(w[0], w[1], w[2], w[3]);
    d4[1] = make_uint4(w[4], w[5], w[6], w[7]);
    d4[2] = make_uint4(w[8], w[9], w[10], w[11]);
    d4[3] = make_uint4(w[12], w[13], w[14], w[15]);
}

// ---- prep_e: bq exact + (-2e) f16 ----------------------------------------
__global__ __launch_bounds__(256) void vq_prep_e(
        const float* __restrict__ emb, float* __restrict__ bq,
        unsigned short* __restrict__ eh) {
    const int g = blockIdx.x * 256 + threadIdx.x;
    if (g >= NUM_EMB) return;
    const float* e = emb + g * EMB_DIM;
    bq[g] = pairwise_sq32(e);
    unsigned short h[32];
#pragma unroll
    for (int c = 0; c < 32; ++c) {
        _Float16 hv = (_Float16)(-2.0f * e[c]);   // *2 exact, single RNE round
        h[c] = __builtin_bit_cast(unsigned short, hv);
    }
    store_row16(eh + (size_t)g * 32, h);
}

// ---- exact-rescore building blocks (verified numpy-fp32 chain) ------------
#define LOADZ(c) float z##c = zp[(size_t)(c) * HW];
#define Z_SQ_A()                                                              \
    float r0 = __fmul_rn(z0, z0), r1 = __fmul_rn(z1, z1);                     \
    float r2 = __fmul_rn(z2, z2), r3 = __fmul_rn(z3, z3);                     \
    float r4 = __fmul_rn(z4, z4), r5 = __fmul_rn(z5, z5);                     \
    float r6 = __fmul_rn(z6, z6), r7 = __fmul_rn(z7, z7);                     \
    r0 = __fadd_rn(r0, __fmul_rn(z8,  z8));  r0 = __fadd_rn(r0, __fmul_rn(z16, z16)); \
    r0 = __fadd_rn(r0, __fmul_rn(z24, z24));                                  \
    r1 = __fadd_rn(r1, __fmul_rn(z9,  z9));  r1 = __fadd_rn(r1, __fmul_rn(z17, z17)); \
    r1 = __fadd_rn(r1, __fmul_rn(z25, z25));                                  \
    r2 = __fadd_rn(r2, __fmul_rn(z10, z10)); r2 = __fadd_rn(r2, __fmul_rn(z18, z18)); \
    r2 = __fadd_rn(r2, __fmul_rn(z26, z26));                                  \
    r3 = __fadd_rn(r3, __fmul_rn(z11, z11)); r3 = __fadd_rn(r3, __fmul_rn(z19, z19)); \
    r3 = __fadd_rn(r3, __fmul_rn(z27, z27));                                  \
    r4 = __fadd_rn(r4, __fmul_rn(z12, z12)); r4 = __fadd_rn(r4, __fmul_rn(z20, z20)); \
    r4 = __fadd_rn(r4, __fmul_rn(z28, z28));                                  \
    r5 = __fadd_rn(r5, __fmul_rn(z13, z13)); r5 = __fadd_rn(r5, __fmul_rn(z21, z21)); \
    r5 = __fadd_rn(r5, __fmul_rn(z29, z29));                                  \
    r6 = __fadd_rn(r6, __fmul_rn(z14, z14)); r6 = __fadd_rn(r6, __fmul_rn(z22, z22)); \
    r6 = __fadd_rn(r6, __fmul_rn(z30, z30));                                  \
    r7 = __fadd_rn(r7, __fmul_rn(z15, z15)); r7 = __fadd_rn(r7, __fmul_rn(z23, z23)); \
    r7 = __fadd_rn(r7, __fmul_rn(z31, z31));                                  \
    const float a = __fadd_rn(                                                \
        __fadd_rn(__fadd_rn(r0, r1), __fadd_rn(r2, r3)),                      \
        __fadd_rn(__fadd_rn(r4, r5), __fadd_rn(r6, r7)));

#define FMA1(k) m = __fmaf_rn(z##k, e[(k)], m);
#define EXACT_KEY(jv)                                                         \
    {                                                                         \
        const float* e = emb + (size_t)(jv) * EMB_DIM;                        \
        float m = 0.0f;                                                       \
        REPEAT32(FMA1)                                                        \
        float d = __fsub_rn(__fadd_rn(a, bq[(jv)]), __fmul_rn(2.0f, m));      \
        unsigned u = __float_as_uint(d);                                      \
        u = (u & 0x80000000u) ? ~u : (u | 0x80000000u);                       \
        unsigned long long kk =                                               \
            ((unsigned long long)u << 32) | (unsigned)(jv);                   \
        if (kk < bestk) bestk = kk;                                           \
    }

// ---- mega filter: scan + classify + rescore + writeback + local fixup -----
// Block = 256 thr = 4 waves; wave: 32 queries (2 tiles); block: 128 queries.
// LDS phase 1: seh/sbq staging (17408 B). Phase 2 (aliased):
// scand/sdest/sBlist/bs.
__global__ __launch_bounds__(256, 4) void vq_filter(
        const float* __restrict__ z, const float* __restrict__ emb,
        const unsigned short* __restrict__ eh,
        const float* __restrict__ bq,
        float* __restrict__ out_zq, float* __restrict__ out_idx) {
    __shared__ __align__(16) char smem[17408];
    _Float16* seh = (_Float16*)smem;           // [0, 16384)  256 rows x 64 B
    float*    sbq = (float*)(smem + 16384);    // [16384, 17408)
    // phase-2 aliases (scan complete, barrier-separated):
    int* scand  = (int*)smem;                  // [0, 2048)    128*4 ints
    int* sdest  = (int*)(smem + 2048);         // [2048, 2560) 128 ints
    int* sBlist = (int*)(smem + 2560);         // [2560, 3072) 128 ints
    unsigned long long* bs =
        (unsigned long long*)(smem + 3072);    // [3072, 5120) 256 u64
    __shared__ int swt[2];

    const int tid  = threadIdx.x;
    const int lane = tid & 63;
    const int wv   = tid >> 6;
    const int cloc = lane & 15, quad = lane >> 4;
    const int qbase = blockIdx.x * 128 + wv * 32;

    // A-fragments from z (f16 RNE); raw floats are NOT kept (reload in P2)
    f16x8 az[2];
#pragma unroll
    for (int t = 0; t < 2; ++t) {
        const int q  = qbase + t * 16 + cloc;
        const int b  = q >> 12;
        const int hw = q & 4095;
        const float* zb = z + ((size_t)b * EMB_DIM + quad * 8) * HW + hw;
#pragma unroll
        for (int k = 0; k < 8; ++k)
            az[t][k] = (_Float16)zb[(size_t)k * HW];   // v_cvt_f16_f32, RNE
    }

    // global packed (value|jts) minima
    float m1[2][4], m2[2][4];
#pragma unroll
    for (int t = 0; t < 2; ++t)
#pragma unroll
        for (int r = 0; r < 4; ++r) { m1[t][r] = 3.4e38f; m2[t][r] = 3.4e38f; }

    const unsigned km = 0xFFFFFFC0u;   // clear low-6 mantissa bits

    for (int ch = 0; ch < 4; ++ch) {
        if (ch) __syncthreads();
        {   // stage 256 codes x 32 f16 = 16 KB + bq chunk
            const uint4* src = (const uint4*)(eh + (size_t)ch * CHUNK * 32);
            uint4* dst = (uint4*)seh;
#pragma unroll
            for (int i = 0; i < 4; ++i) dst[i * 256 + tid] = src[i * 256 + tid];
            sbq[tid] = bq[ch * CHUNK + tid];
        }
        __syncthreads();

        // chunk-local packed minima (jt in low 4 bits; ch OR'd in at merge)
        float c1[2][4], c2[2][4];
#pragma unroll
        for (int t = 0; t < 2; ++t)
#pragma unroll
            for (int r = 0; r < 4; ++r) { c1[t][r] = 3.4e38f; c2[t][r] = 3.4e38f; }

#pragma unroll
        for (int jt = 0; jt < 16; ++jt) {
            const int row = jt * 16 + cloc;
            f16x8 ef = *(const f16x8*)(seh + row * 32 + quad * 8); // b128
            const float bqv = sbq[row];
#pragma unroll
            for (int t = 0; t < 2; ++t) {
                f32x4 acc = {bqv, bqv, bqv, bqv};
                acc = __builtin_amdgcn_mfma_f32_16x16x32_f16(az[t], ef, acc, 0, 0, 0);
#pragma unroll
                for (int r = 0; r < 4; ++r) {
                    // pack jt (inline const after unroll) into low bits
                    const float kv = __uint_as_float(
                        (__float_as_uint(acc[r]) & km) | (unsigned)jt);
                    c2[t][r] = __builtin_amdgcn_fmed3f(kv, c1[t][r], c2[t][r]);
                    c1[t][r] = fminf(c1[t][r], kv);
                }
            }
        }

        // merge chunk minima into global (OR ch bits into packed index)
        const unsigned chb = (unsigned)ch << 4;
#pragma unroll
        for (int t = 0; t < 2; ++t)
#pragma unroll
            for (int r = 0; r < 4; ++r) {
                const float a1 = __uint_as_float(__float_as_uint(c1[t][r]) | chb);
                const float a2 = __uint_as_float(__float_as_uint(c2[t][r]) | chb);
                m2[t][r] = fminf(fmaxf(m1[t][r], a1), fminf(m2[t][r], a2));
                m1[t][r] = fminf(m1[t][r], a1);
            }
    }
    __syncthreads();   // scan done everywhere; staging LDS may be reused

    // per-query global min across the 16 cloc lanes (packed floats)
    float g[2][4];
#pragma unroll
    for (int t = 0; t < 2; ++t)
#pragma unroll
        for (int r = 0; r < 4; ++r) g[t][r] = m1[t][r];
#pragma unroll
    for (int off = 1; off < 16; off <<= 1)
#pragma unroll
        for (int t = 0; t < 2; ++t)
#pragma unroll
            for (int r = 0; r < 4; ++r)
                g[t][r] = fminf(g[t][r], __shfl_xor(g[t][r], off, 64));

    // classification -> LDS, no atomics (ballot-prefix candidate slots)
#pragma unroll
    for (int t = 0; t < 2; ++t)
#pragma unroll
        for (int r = 0; r < 4; ++r) {
            const float thr = g[t][r] + MARGIN;
            const int   ql  = wv * 32 + t * 16 + quad * 4 + r;
            const bool  f1  = m1[t][r] <= thr;
            const bool  f2  = m2[t][r] <= thr;
            const unsigned long long b1 = __ballot(f1);
            const unsigned long long b2 = __ballot(f2);
            const unsigned mk1 = (unsigned)(b1 >> (quad * 16)) & 0xFFFFu;
            const unsigned mk2 = (unsigned)(b2 >> (quad * 16)) & 0xFFFFu;
            const int pc  = __popc(mk1);
            const int ldr = __ffs(mk1) - 1;   // mk1 != 0 (global-min lane)
            if (mk2 | (unsigned)(pc > 4)) {
                if (cloc == ldr) sdest[ql] = 5;
            } else {
                if (f1)
                    scand[(ql << 2) + __popc(mk1 & ((1u << cloc) - 1u))] =
                        (int)(__float_as_uint(m1[t][r]) & 63u) * 16 + cloc;
                if (cloc == ldr) sdest[ql] = pc;
            }
        }
    __syncthreads();

    // local-B compaction (no atomics) + exact rescore for pc 2..4
    int d = 0, pre = 0;
    if (tid < 128) {
        d = sdest[tid];
        const unsigned long long mB = __ballot(d == 5);
        pre = (int)__popcll(mB & ((1ull << lane) - 1ull));
        if (lane == 0) swt[tid >> 6] = (int)__popcll(mB);
    }
    __syncthreads();
    int myidx = 0;
    if (tid < 128) {
        if (d == 5) {
            sBlist[((tid >> 6) ? swt[0] : 0) + pre] = tid;
        } else if (d == 1) {
            myidx = scand[tid << 2];
        } else {
            // exact rescore; z reloaded from global (L2-hot, coalesced)
            const int n  = blockIdx.x * 128 + tid;
            const int bb = n >> 12;
            const int hh = n & 4095;
            const float* zp = z + (size_t)bb * EMB_DIM * HW + hh;
            REPEAT32(LOADZ)
            Z_SQ_A()
            unsigned long long bestk = ~0ull;
            for (int k = 0; k < d; ++k) {
                const int jv = scand[(tid << 2) + k];
                EXACT_KEY(jv)
            }
            myidx = (int)(unsigned)(bestk & 0xffffffffu);
        }
    }
    __syncthreads();   // sBlist visible to all

    // writeback: idx + z_q for all non-B queries (coalesced across tid)
    if (tid < 128 && d != 5) {
        const int n    = blockIdx.x * 128 + tid;
        out_idx[n] = (float)myidx;
        const int bb = n >> 12;
        const int hh = n & 4095;
        const float4* er = (const float4*)(emb + (size_t)myidx * EMB_DIM);
        float* op = out_zq + (size_t)bb * EMB_DIM * HW + hh;
#pragma unroll
        for (int c4 = 0; c4 < 8; ++c4) {
            float4 v = er[c4];
            op[(size_t)(c4 * 4 + 0) * HW] = v.x;
            op[(size_t)(c4 * 4 + 1) * HW] = v.y;
            op[(size_t)(c4 * 4 + 2) * HW] = v.z;
            op[(size_t)(c4 * 4 + 3) * HW] = v.w;
        }
    }

    // in-block fixup: exact full 1024-code scan per local-B query
    const int nB = swt[0] + swt[1];
    for (int ib = 0; ib < nB; ++ib) {
        const int ql = sBlist[ib];
        const int n  = blockIdx.x * 128 + ql;
        const int bb = n >> 12;
        const int hh = n & 4095;
        const float* zp = z + (size_t)bb * EMB_DIM * HW + hh;  // broadcast
        REPEAT32(LOADZ)
        Z_SQ_A()
        unsigned long long bestk = ~0ull;
#pragma unroll
        for (int k = 0; k < 4; ++k) { const int jv = tid * 4 + k; EXACT_KEY(jv) }
        bs[tid] = bestk;
        __syncthreads();
        for (int off = 128; off > 0; off >>= 1) {
            if (tid < off && bs[tid + off] < bs[tid]) bs[tid] = bs[tid + off];
            __syncthreads();
        }
        const int fb = (int)(unsigned)(bs[0] & 0xffffffffu);
        if (tid == 0) out_idx[n] = (float)fb;
        if (tid < EMB_DIM)
            out_zq[(size_t)bb * EMB_DIM * HW + (size_t)tid * HW + hh] =
                emb[(size_t)fb * EMB_DIM + tid];
        __syncthreads();
    }
}

// ================== proven R7/R5 exhaustive fallback =======================
#define SCAN_GROUP4(j)                                                        \
    {                                                                         \
        const float* e = emb + (size_t)(j) * EMB_DIM;                         \
        const float bq0 = bq[(j) + 0], bq1 = bq[(j) + 1];                     \
        const float bq2 = bq[(j) + 2], bq3 = bq[(j) + 3];                     \
        float m0 = 0.0f, m1 = 0.0f, m2 = 0.0f, m3 = 0.0f;                     \
        REPEAT32(FMA_K)                                                       \
        float d0 = __fsub_rn(__fadd_rn(a, bq0), __fmul_rn(2.0f, m0));         \
        float d1 = __fsub_rn(__fadd_rn(a, bq1), __fmul_rn(2.0f, m1));         \
        float d2 = __fsub_rn(__fadd_rn(a, bq2), __fmul_rn(2.0f, m2));         \
        float d3 = __fsub_rn(__fadd_rn(a, bq3), __fmul_rn(2.0f, m3));         \
        if (d0 < best) { best = d0; bidx = (j) + 0; }                         \
        if (d1 < best) { best = d1; bidx = (j) + 1; }                         \
        if (d2 < best) { best = d2; bidx = (j) + 2; }                         \
        if (d3 < best) { best = d3; bidx = (j) + 3; }                         \
    }
#define FMA_K(k) \
        m0 = __fmaf_rn(z##k, e[0 * EMB_DIM + (k)], m0); \
        m1 = __fmaf_rn(z##k, e[1 * EMB_DIM + (k)], m1); \
        m2 = __fmaf_rn(z##k, e[2 * EMB_DIM + (k)], m2); \
        m3 = __fmaf_rn(z##k, e[3 * EMB_DIM + (k)], m3);

__global__ __launch_bounds__(256) void vq_sqnorm_kernel(
        const float* __restrict__ emb, float* __restrict__ bq) {
    int j = blockIdx.x * 256 + threadIdx.x;
    if (j < NUM_EMB) bq[j] = pairwise_sq32(emb + j * EMB_DIM);
}

__global__ __launch_bounds__(128, 4) void vq_partial_kernel(
        const float* __restrict__ z, const float* __restrict__ emb,
        const float* __restrict__ bq, unsigned long long* __restrict__ pk) {
    const int n  = blockIdx.x * 128 + threadIdx.x;
    const int b  = n >> 12;
    const int hw = n & 4095;
    const float* zp = z + (size_t)b * EMB_DIM * HW + hw;
    REPEAT32(LOADZ)
    Z_SQ_A()
    const int j0 = blockIdx.y * CODES_PER;
    float best = 3.4e38f;
    int   bidx = j0;
    for (int j = j0; j < j0 + CODES_PER; j += 4) SCAN_GROUP4(j)
    pk[(size_t)blockIdx.y * N_TOT + n] =
        ((unsigned long long)__float_as_uint(best) << 32) | (unsigned)bidx;
}

__global__ __launch_bounds__(256, 2) void vq_main_kernel(
        const float* __restrict__ z, const float* __restrict__ emb,
        const float* __restrict__ bq, float* __restrict__ out_zq,
        float* __restrict__ out_idx) {
    const int n  = blockIdx.x * 256 + threadIdx.x;
    const int b  = n >> 12;
    const int hw = n & 4095;
    const float* zp = z + (size_t)b * EMB_DIM * HW + hw;
    REPEAT32(LOADZ)
    Z_SQ_A()
    float best = 3.4e38f;
    int   bidx = 0;
    for (int j = 0; j < NUM_EMB; j += 4) SCAN_GROUP4(j)
    out_idx[n] = (float)bidx;
    const float* eb = emb + (size_t)bidx * EMB_DIM;
    float* op = out_zq + (size_t)b * EMB_DIM * HW + hw;
#pragma unroll
    for (int cc = 0; cc < EMB_DIM; ++cc) op[(size_t)cc * HW] = eb[cc];
}

__global__ __launch_bounds__(256) void vq_combine_kernel(
        const float* __restrict__ emb,
        const unsigned long long* __restrict__ pk,
        float* __restrict__ out_zq, float* __restrict__ out_idx) {
    const int n = blockIdx.x * 256 + threadIdx.x;
    unsigned long long m = pk[n];
#pragma unroll
    for (int y = 1; y < NSPLIT; ++y) {
        unsigned long long v = pk[(size_t)y * N_TOT + n];
        if (v < m) m = v;
    }
    const int bidx = (int)(unsigned)(m & 0xffffffffu);
    out_idx[n] = (float)bidx;
    const int b  = n >> 12;
    const int hw = n & 4095;
    const float* eb = emb + (size_t)bidx * EMB_DIM;
    float* op = out_zq + (size_t)b * EMB_DIM * HW + hw;
#pragma unroll
    for (int cc = 0; cc < EMB_DIM; ++cc) op[(size_t)cc * HW] = eb[cc];
}

extern "C" void kernel_launch(void* const* d_in, const int* in_sizes, int n_in,
                              void* d_out, int out_size, void* d_ws,
                              size_t ws_size, hipStream_t stream) {
    const float* z   = (const float*)d_in[0];
    const float* emb = (const float*)d_in[1];
    char* ws = (char*)d_ws;
    float* out0 = (float*)d_out;
    float* out1 = out0 + (size_t)BATCH * EMB_DIM * HW;

    if (ws_size >= WS_NEED) {
        float*          bq = (float*)(ws + OFF_BQ);
        unsigned short* eh = (unsigned short*)(ws + OFF_EH);

        vq_prep_e<<<4, 256, 0, stream>>>(emb, bq, eh);
        vq_filter<<<N_TOT / 128, 256, 0, stream>>>(z, emb, eh, bq,
                                                   out0, out1);
    } else if (ws_size >= WS_NEED_R7) {
        float* bq = (float*)ws;
        unsigned long long* pk = (unsigned long long*)(ws + 4096);
        vq_sqnorm_kernel<<<NUM_EMB / 256, 256, 0, stream>>>(emb, bq);
        vq_partial_kernel<<<dim3(N_TOT / 128, NSPLIT), 128, 0, stream>>>(
            z, emb, bq, pk);
        vq_combine_kernel<<<N_TOT / 256, 256, 0, stream>>>(emb, pk, out0, out1);
    } else {
        float* bq = (float*)ws;
        vq_sqnorm_kernel<<<NUM_EMB / 256, 256, 0, stream>>>(emb, bq);
        vq_main_kernel<<<N_TOT / 256, 256, 0, stream>>>(z, emb, bq, out0, out1);
    }
}